// Round 3
// baseline (441.458 us; speedup 1.0000x reference)
//
#include <hip/hip_runtime.h>
#include <hip/hip_bf16.h>

typedef __attribute__((ext_vector_type(8))) short bf16x8;
typedef __attribute__((ext_vector_type(4))) float f32x4;
typedef __attribute__((ext_vector_type(2))) float f32x2;

#define B_SZ   4096
#define K1     25
#define K2     10
#define M_L1   45056   /* B*(1+K2) */
#define D      256
#define K_DIM  512
#define N_NODES 200000

static __device__ __forceinline__ unsigned short f2bf(float f) {
    union { float f; unsigned u; } v; v.f = f;
    return (unsigned short)((v.u + 0x7fffu + ((v.u >> 16) & 1u)) >> 16);
}
static __device__ __forceinline__ float bf2f(unsigned short h) {
    union { unsigned u; float f; } v; v.u = ((unsigned)h) << 16;
    return v.f;
}

// ---- convert features fp32 -> fp8 e4m3 (51.2M elems) + W1/W2 -> bf16, one pass ----
__global__ __launch_bounds__(256)
void convert_all(const float* __restrict__ f, unsigned* __restrict__ f8,
                 const float* __restrict__ W1, const float* __restrict__ W2,
                 unsigned short* __restrict__ W1b, unsigned short* __restrict__ W2b) {
    const size_t i = ((size_t)blockIdx.x * 256 + threadIdx.x) * 8;
    const float4 a = *(const float4*)(f + i);
    const float4 b = *(const float4*)(f + i + 4);
    unsigned u0 = 0, u1 = 0;
    u0 = __builtin_amdgcn_cvt_pk_fp8_f32(a.x, a.y, u0, false);
    u0 = __builtin_amdgcn_cvt_pk_fp8_f32(a.z, a.w, u0, true);
    u1 = __builtin_amdgcn_cvt_pk_fp8_f32(b.x, b.y, u1, false);
    u1 = __builtin_amdgcn_cvt_pk_fp8_f32(b.z, b.w, u1, true);
    uint2 r; r.x = u0; r.y = u1;
    *(uint2*)(f8 + (i >> 2)) = r;
    const int j = blockIdx.x * 256 + threadIdx.x;
    if (j < D * K_DIM) {           // 131072 = 256*512 elements each
        W1b[j] = f2bf(W1[j]);
        W2b[j] = f2bf(W2[j]);
    }
}

// ============================================================================
// fused_l1: gather+mean -> LDS A-tile (bf16, XOR-swizzled) + GEMM1 + relu.
//   BM=32, 512 threads (8 waves = 2M x 4N, wave tile 16x64).
//   LDS = As only (32 KB) -> 2 blocks/CU (launch_bounds(512,4), VGPR<=128):
//   4 waves/SIMD during the latency-bound gather phase.
//   B (W1b, 256 KB, L2-resident) is NOT staged in LDS: fragments are loaded
//   straight from global into a register double-buffer, prefetching step t+1
//   under step t's MFMAs. Statically indexed (full unroll) per rule #20.
//   Only ONE barrier in the kernel (As write -> As read). No vmcnt drains.
//   As swizzle: 16B chunk c of row r stored at c^(r&7) -> fragment
//   ds_read_b128 is 2-lane/bank-group (free, m136).
// ============================================================================
__global__ __launch_bounds__(512, 4)
void fused_l1(const float* __restrict__ feat,
              const unsigned* __restrict__ f8,
              const int* __restrict__ nodes_batch,
              const int* __restrict__ neigh2,
              const int* __restrict__ neigh1,
              const unsigned short* __restrict__ W,
              unsigned short* __restrict__ h1) {
    __shared__ unsigned short As[32 * 512];      // 32 KB
    const int tid  = threadIdx.x;
    const int w    = tid >> 6, lane = tid & 63;
    const int quad = lane >> 4, l16 = lane & 15;
    const int wm   = (w >> 2) << 4;   // 0 / 16
    const int wn   = (w & 3) << 6;    // 0,64,128,192
    const size_t row0 = (size_t)blockIdx.x * 32;

    // B fragment base: lane reads W[(wn + i*16 + l16)*512 + t*64 + ks*32 + quad*8]
    const unsigned short* bBase = W + (size_t)(wn + l16) * K_DIM + (quad << 3);

    bf16x8 bp[2][8];   // [buf][ks*4+i], statically indexed via full unroll
    #pragma unroll
    for (int ks = 0; ks < 2; ++ks)
        #pragma unroll
        for (int i = 0; i < 4; ++i)
            bp[0][ks * 4 + i] = *(const bf16x8*)(bBase + (size_t)(i * 16) * K_DIM + ks * 32);

    // ---- gather + mean -> As (4 rows per wave) ----
    #pragma unroll 2
    for (int rr = 0; rr < 4; ++rr) {
        const int r = (w << 2) + rr;
        const int m = (int)row0 + r;
        const int self_node = (m < B_SZ) ? nodes_batch[m] : neigh2[m - B_SZ];
        const int* nb = neigh1 + (size_t)m * K1;
        int idxv = (lane < K1) ? nb[lane] : 0;
        const float4 s = *(const float4*)(feat + (size_t)self_node * D + (lane << 2));
        unsigned q[K1];
        #pragma unroll
        for (int j = 0; j < K1; ++j) {
            const int node = __shfl(idxv, j);
            q[j] = f8[(size_t)node * (D / 4) + lane];
        }
        float a0 = 0.f, a1 = 0.f, a2 = 0.f, a3 = 0.f;
        #pragma unroll
        for (int j = 0; j < K1; ++j) {
            const f32x2 lo = __builtin_amdgcn_cvt_pk_f32_fp8(q[j], false);
            const f32x2 hi = __builtin_amdgcn_cvt_pk_f32_fp8(q[j], true);
            a0 += lo.x; a1 += lo.y; a2 += hi.x; a3 += hi.y;
        }
        const float inv = 1.0f / (float)K1;
        const int e0 = lane << 2;                  // self elems [0,256)
        const int p0 = (e0 >> 3) ^ (r & 7);
        *(ushort4*)&As[r * 512 + (p0 << 3) + (e0 & 7)] =
            make_ushort4(f2bf(s.x), f2bf(s.y), f2bf(s.z), f2bf(s.w));
        const int e1 = D + (lane << 2);            // agg elems [256,512)
        const int p1 = (e1 >> 3) ^ (r & 7);
        *(ushort4*)&As[r * 512 + (p1 << 3) + (e1 & 7)] =
            make_ushort4(f2bf(a0 * inv), f2bf(a1 * inv), f2bf(a2 * inv), f2bf(a3 * inv));
    }

    __syncthreads();

    // ---- GEMM: register-double-buffered B, zero barriers ----
    f32x4 acc[4];
    #pragma unroll
    for (int j = 0; j < 4; ++j) acc[j] = (f32x4){0.f, 0.f, 0.f, 0.f};

    #pragma unroll
    for (int t = 0; t < 8; ++t) {
        if (t < 7) {
            #pragma unroll
            for (int ks = 0; ks < 2; ++ks)
                #pragma unroll
                for (int i = 0; i < 4; ++i)
                    bp[(t + 1) & 1][ks * 4 + i] =
                        *(const bf16x8*)(bBase + (size_t)(i * 16) * K_DIM + (t + 1) * 64 + ks * 32);
        }
        #pragma unroll
        for (int ks = 0; ks < 2; ++ks) {
            const int row = wm + l16;
            const int ch  = (t << 3) + (ks << 2) + quad;   // 16B chunk in [0,64)
            const bf16x8 af = *(const bf16x8*)&As[row * 512 + ((ch ^ (row & 7)) << 3)];
            #pragma unroll
            for (int ni = 0; ni < 4; ++ni)
                acc[ni] = __builtin_amdgcn_mfma_f32_16x16x32_bf16(
                    af, bp[t & 1][ks * 4 + ni], acc[ni], 0, 0, 0);
        }
    }

    #pragma unroll
    for (int ni = 0; ni < 4; ++ni)
        #pragma unroll
        for (int rg = 0; rg < 4; ++rg) {
            const size_t gm = row0 + wm + quad * 4 + rg;
            const size_t gn = (size_t)wn + ni * 16 + l16;
            float v = acc[ni][rg];
            v = v > 0.f ? v : 0.f;
            h1[gm * D + gn] = f2bf(v);
        }
}

// ============================================================================
// fused_l2: agg2 -> LDS A-tile + GEMM2 + relu -> out (fp32).
//   BM=16, 256 threads (4 waves, each all 16 rows x its 64-col slice).
//   Same register-double-buffered B scheme, LDS = 16 KB, one barrier.
// ============================================================================
__global__ __launch_bounds__(256, 4)
void fused_l2(const unsigned short* __restrict__ h1,
              const unsigned short* __restrict__ W,
              float* __restrict__ out) {
    __shared__ unsigned short As[16 * 512];      // 16 KB
    const int tid  = threadIdx.x;
    const int w    = tid >> 6, lane = tid & 63;
    const int quad = lane >> 4, l16 = lane & 15;
    const int wn   = w << 6;
    const size_t row0 = (size_t)blockIdx.x * 16;

    const unsigned short* bBase = W + (size_t)(wn + l16) * K_DIM + (quad << 3);

    bf16x8 bp[2][8];
    #pragma unroll
    for (int ks = 0; ks < 2; ++ks)
        #pragma unroll
        for (int i = 0; i < 4; ++i)
            bp[0][ks * 4 + i] = *(const bf16x8*)(bBase + (size_t)(i * 16) * K_DIM + ks * 32);

    // ---- build A-tile: [h1[b] | mean_k h1[B + b*K2 + k]] (4 rows per wave) ----
    #pragma unroll 2
    for (int rr = 0; rr < 4; ++rr) {
        const int r = (w << 2) + rr;
        const size_t b = row0 + r;
        const ushort4 sv = *(const ushort4*)&h1[b * D + (lane << 2)];
        float a0 = 0.f, a1 = 0.f, a2 = 0.f, a3 = 0.f;
        #pragma unroll
        for (int k = 0; k < K2; ++k) {
            const ushort4 v = *(const ushort4*)&h1[(size_t)(B_SZ + b * K2 + k) * D + (lane << 2)];
            a0 += bf2f(v.x); a1 += bf2f(v.y); a2 += bf2f(v.z); a3 += bf2f(v.w);
        }
        const float inv = 1.0f / (float)K2;
        const int e0 = lane << 2;
        const int p0 = (e0 >> 3) ^ (r & 7);
        *(ushort4*)&As[r * 512 + (p0 << 3) + (e0 & 7)] = sv;   // self: already bf16
        const int e1 = D + (lane << 2);
        const int p1 = (e1 >> 3) ^ (r & 7);
        *(ushort4*)&As[r * 512 + (p1 << 3) + (e1 & 7)] =
            make_ushort4(f2bf(a0 * inv), f2bf(a1 * inv), f2bf(a2 * inv), f2bf(a3 * inv));
    }

    __syncthreads();

    f32x4 acc[4];
    #pragma unroll
    for (int j = 0; j < 4; ++j) acc[j] = (f32x4){0.f, 0.f, 0.f, 0.f};

    #pragma unroll
    for (int t = 0; t < 8; ++t) {
        if (t < 7) {
            #pragma unroll
            for (int ks = 0; ks < 2; ++ks)
                #pragma unroll
                for (int i = 0; i < 4; ++i)
                    bp[(t + 1) & 1][ks * 4 + i] =
                        *(const bf16x8*)(bBase + (size_t)(i * 16) * K_DIM + (t + 1) * 64 + ks * 32);
        }
        #pragma unroll
        for (int ks = 0; ks < 2; ++ks) {
            const int row = l16;
            const int ch  = (t << 3) + (ks << 2) + quad;
            const bf16x8 af = *(const bf16x8*)&As[row * 512 + ((ch ^ (row & 7)) << 3)];
            #pragma unroll
            for (int ni = 0; ni < 4; ++ni)
                acc[ni] = __builtin_amdgcn_mfma_f32_16x16x32_bf16(
                    af, bp[t & 1][ks * 4 + ni], acc[ni], 0, 0, 0);
        }
    }

    #pragma unroll
    for (int ni = 0; ni < 4; ++ni)
        #pragma unroll
        for (int rg = 0; rg < 4; ++rg) {
            const size_t gm = row0 + quad * 4 + rg;
            const size_t gn = (size_t)wn + ni * 16 + l16;
            float v = acc[ni][rg];
            out[gm * D + gn] = v > 0.f ? v : 0.f;
        }
}

extern "C" void kernel_launch(void* const* d_in, const int* in_sizes, int n_in,
                              void* d_out, int out_size, void* d_ws, size_t ws_size,
                              hipStream_t stream) {
    const float* feat        = (const float*)d_in[0];
    const float* W1          = (const float*)d_in[1];
    const float* W2          = (const float*)d_in[2];
    const int*   nodes_batch = (const int*)d_in[3];
    const int*   neigh2      = (const int*)d_in[4];
    const int*   neigh1      = (const int*)d_in[5];
    float* out = (float*)d_out;

    char* ws = (char*)d_ws;
    unsigned*       f8  = (unsigned*)(ws);                    // 51,200,000 B
    unsigned short* h1  = (unsigned short*)(ws + 51200000);   // 23,068,672 B
    unsigned short* W1b = (unsigned short*)(ws + 51200000 + 23068672);           // 262,144 B
    unsigned short* W2b = (unsigned short*)(ws + 51200000 + 23068672 + 262144);  // 262,144 B

    convert_all<<<25000, 256, 0, stream>>>(feat, f8, W1, W2, W1b, W2b);
    fused_l1<<<M_L1 / 32, 512, 0, stream>>>(feat, f8, nodes_batch, neigh2, neigh1, W1b, h1);
    fused_l2<<<B_SZ / 16, 256, 0, stream>>>(h1, W2b, out);
}

// Round 4
// 426.144 us; speedup vs baseline: 1.0359x; 1.0359x over previous
//
#include <hip/hip_runtime.h>
#include <hip/hip_bf16.h>

typedef __attribute__((ext_vector_type(8))) short bf16x8;
typedef __attribute__((ext_vector_type(4))) float f32x4;
typedef __attribute__((ext_vector_type(2))) float f32x2;

#define B_SZ   4096
#define K1     25
#define K2     10
#define M_L1   45056   /* B*(1+K2) */
#define D      256
#define K_DIM  512
#define N_NODES 200000

static __device__ __forceinline__ unsigned short f2bf(float f) {
    union { float f; unsigned u; } v; v.f = f;
    return (unsigned short)((v.u + 0x7fffu + ((v.u >> 16) & 1u)) >> 16);
}
static __device__ __forceinline__ float bf2f(unsigned short h) {
    union { unsigned u; float f; } v; v.u = ((unsigned)h) << 16;
    return v.f;
}

// ---- convert features fp32 -> fp8 e4m3 (51.2M elems) + W1/W2 -> bf16, one pass ----
__global__ __launch_bounds__(256)
void convert_all(const float* __restrict__ f, unsigned* __restrict__ f8,
                 const float* __restrict__ W1, const float* __restrict__ W2,
                 unsigned short* __restrict__ W1b, unsigned short* __restrict__ W2b) {
    const size_t i = ((size_t)blockIdx.x * 256 + threadIdx.x) * 8;
    const float4 a = *(const float4*)(f + i);
    const float4 b = *(const float4*)(f + i + 4);
    unsigned u0 = 0, u1 = 0;
    u0 = __builtin_amdgcn_cvt_pk_fp8_f32(a.x, a.y, u0, false);
    u0 = __builtin_amdgcn_cvt_pk_fp8_f32(a.z, a.w, u0, true);
    u1 = __builtin_amdgcn_cvt_pk_fp8_f32(b.x, b.y, u1, false);
    u1 = __builtin_amdgcn_cvt_pk_fp8_f32(b.z, b.w, u1, true);
    uint2 r; r.x = u0; r.y = u1;
    *(uint2*)(f8 + (i >> 2)) = r;
    const int j = blockIdx.x * 256 + threadIdx.x;
    if (j < D * K_DIM) {           // 131072 = 256*512 elements each
        W1b[j] = f2bf(W1[j]);
        W2b[j] = f2bf(W2[j]);
    }
}

// ============================================================================
// fused_l1: gather+mean -> LDS A-tile (bf16, XOR-swizzled) + GEMM1 + relu.
//   BM=32, 512 threads (8 waves = 2M x 4N, wave tile 16x64), LDS = 32 KB.
//   Gather: indices extracted with v_readlane (SALU, no ds_bpermute/lgkm
//   stall) -> 25 global loads per row issue as one burst with SGPR bases;
//   2 rows in flight per wave (~52 outstanding 256B loads).
//   GEMM: B (W1b, L2-resident) loaded per K-step into a SINGLE register
//   buffer bp[8] (32 VGPR) -> peak pressure ~80 regs, no spill (round-3's
//   bp[2][8] forced VGPR=64 => spill/de-pipeline, the regression).
//   One barrier total. As swizzle: chunk c of row r at c^(r&7).
// ============================================================================
__global__ __launch_bounds__(512, 4)
void fused_l1(const float* __restrict__ feat,
              const unsigned* __restrict__ f8,
              const int* __restrict__ nodes_batch,
              const int* __restrict__ neigh2,
              const int* __restrict__ neigh1,
              const unsigned short* __restrict__ W,
              unsigned short* __restrict__ h1) {
    __shared__ unsigned short As[32 * 512];      // 32 KB
    const int tid  = threadIdx.x;
    const int w    = tid >> 6, lane = tid & 63;
    const int quad = lane >> 4, l16 = lane & 15;
    const int wm   = (w >> 2) << 4;   // 0 / 16
    const int wn   = (w & 3) << 6;    // 0,64,128,192
    const size_t row0 = (size_t)blockIdx.x * 32;

    // ---- gather + mean -> As: 4 rows/wave, processed as 2 pairs ----
    #pragma unroll
    for (int rp = 0; rp < 2; ++rp) {
        const int rA = (w << 2) + rp * 2;
        const int rB = rA + 1;
        const int mA = (int)row0 + rA;
        const int mB = mA + 1;
        int selfA = (mA < B_SZ) ? nodes_batch[mA] : neigh2[mA - B_SZ];
        int selfB = (mB < B_SZ) ? nodes_batch[mB] : neigh2[mB - B_SZ];
        selfA = __builtin_amdgcn_readfirstlane(selfA);
        selfB = __builtin_amdgcn_readfirstlane(selfB);
        const float4 sA = *(const float4*)(feat + (size_t)selfA * D + (lane << 2));
        const float4 sB = *(const float4*)(feat + (size_t)selfB * D + (lane << 2));
        const int ivA = (lane < K1) ? neigh1[(size_t)mA * K1 + lane] : 0;
        const int ivB = (lane < K1) ? neigh1[(size_t)mB * K1 + lane] : 0;
        unsigned qA[K1], qB[K1];
        #pragma unroll
        for (int j = 0; j < K1; ++j) {
            const int n = __builtin_amdgcn_readlane(ivA, j);   // SGPR, no LDS hop
            qA[j] = f8[(size_t)n * (D / 4) + lane];
        }
        #pragma unroll
        for (int j = 0; j < K1; ++j) {
            const int n = __builtin_amdgcn_readlane(ivB, j);
            qB[j] = f8[(size_t)n * (D / 4) + lane];
        }
        float aA0 = 0.f, aA1 = 0.f, aA2 = 0.f, aA3 = 0.f;
        float aB0 = 0.f, aB1 = 0.f, aB2 = 0.f, aB3 = 0.f;
        #pragma unroll
        for (int j = 0; j < K1; ++j) {
            const f32x2 lo = __builtin_amdgcn_cvt_pk_f32_fp8(qA[j], false);
            const f32x2 hi = __builtin_amdgcn_cvt_pk_f32_fp8(qA[j], true);
            aA0 += lo.x; aA1 += lo.y; aA2 += hi.x; aA3 += hi.y;
        }
        #pragma unroll
        for (int j = 0; j < K1; ++j) {
            const f32x2 lo = __builtin_amdgcn_cvt_pk_f32_fp8(qB[j], false);
            const f32x2 hi = __builtin_amdgcn_cvt_pk_f32_fp8(qB[j], true);
            aB0 += lo.x; aB1 += lo.y; aB2 += hi.x; aB3 += hi.y;
        }
        const float inv = 1.0f / (float)K1;
        const int e0 = lane << 2;                  // self elems [0,256)
        const int e1 = D + (lane << 2);            // agg elems [256,512)
        {
            const int p0 = (e0 >> 3) ^ (rA & 7);
            *(ushort4*)&As[rA * 512 + (p0 << 3) + (e0 & 7)] =
                make_ushort4(f2bf(sA.x), f2bf(sA.y), f2bf(sA.z), f2bf(sA.w));
            const int p1 = (e1 >> 3) ^ (rA & 7);
            *(ushort4*)&As[rA * 512 + (p1 << 3) + (e1 & 7)] =
                make_ushort4(f2bf(aA0 * inv), f2bf(aA1 * inv), f2bf(aA2 * inv), f2bf(aA3 * inv));
        }
        {
            const int p0 = (e0 >> 3) ^ (rB & 7);
            *(ushort4*)&As[rB * 512 + (p0 << 3) + (e0 & 7)] =
                make_ushort4(f2bf(sB.x), f2bf(sB.y), f2bf(sB.z), f2bf(sB.w));
            const int p1 = (e1 >> 3) ^ (rB & 7);
            *(ushort4*)&As[rB * 512 + (p1 << 3) + (e1 & 7)] =
                make_ushort4(f2bf(aB0 * inv), f2bf(aB1 * inv), f2bf(aB2 * inv), f2bf(aB3 * inv));
        }
    }

    __syncthreads();

    // ---- GEMM: single-buffered register B (32 VGPR), zero extra barriers ----
    const unsigned short* bBase = W + (size_t)(wn + l16) * K_DIM + (quad << 3);
    f32x4 acc[4];
    #pragma unroll
    for (int j = 0; j < 4; ++j) acc[j] = (f32x4){0.f, 0.f, 0.f, 0.f};

    #pragma unroll
    for (int t = 0; t < 8; ++t) {
        bf16x8 bp[8];
        #pragma unroll
        for (int ks = 0; ks < 2; ++ks)
            #pragma unroll
            for (int i = 0; i < 4; ++i)
                bp[ks * 4 + i] = *(const bf16x8*)(bBase + (size_t)(i * 16) * K_DIM + t * 64 + ks * 32);
        #pragma unroll
        for (int ks = 0; ks < 2; ++ks) {
            const int row = wm + l16;
            const int ch  = (t << 3) + (ks << 2) + quad;   // 16B chunk in [0,64)
            const bf16x8 af = *(const bf16x8*)&As[row * 512 + ((ch ^ (row & 7)) << 3)];
            #pragma unroll
            for (int ni = 0; ni < 4; ++ni)
                acc[ni] = __builtin_amdgcn_mfma_f32_16x16x32_bf16(
                    af, bp[ks * 4 + ni], acc[ni], 0, 0, 0);
        }
    }

    #pragma unroll
    for (int ni = 0; ni < 4; ++ni)
        #pragma unroll
        for (int rg = 0; rg < 4; ++rg) {
            const size_t gm = row0 + wm + quad * 4 + rg;
            const size_t gn = (size_t)wn + ni * 16 + l16;
            float v = acc[ni][rg];
            v = v > 0.f ? v : 0.f;
            h1[gm * D + gn] = f2bf(v);
        }
}

// ============================================================================
// fused_l2: agg2 -> LDS A-tile + GEMM2 + relu -> out (fp32).
//   BM=16, 256 threads (4 waves, each all 16 rows x its 64-col slice).
//   Single-buffered register B, LDS = 16 KB, one barrier.
// ============================================================================
__global__ __launch_bounds__(256, 4)
void fused_l2(const unsigned short* __restrict__ h1,
              const unsigned short* __restrict__ W,
              float* __restrict__ out) {
    __shared__ unsigned short As[16 * 512];      // 16 KB
    const int tid  = threadIdx.x;
    const int w    = tid >> 6, lane = tid & 63;
    const int quad = lane >> 4, l16 = lane & 15;
    const int wn   = w << 6;
    const size_t row0 = (size_t)blockIdx.x * 16;

    // ---- build A-tile: [h1[b] | mean_k h1[B + b*K2 + k]] (4 rows per wave) ----
    #pragma unroll 2
    for (int rr = 0; rr < 4; ++rr) {
        const int r = (w << 2) + rr;
        const size_t b = row0 + r;
        const ushort4 sv = *(const ushort4*)&h1[b * D + (lane << 2)];
        float a0 = 0.f, a1 = 0.f, a2 = 0.f, a3 = 0.f;
        #pragma unroll
        for (int k = 0; k < K2; ++k) {
            const ushort4 v = *(const ushort4*)&h1[(size_t)(B_SZ + b * K2 + k) * D + (lane << 2)];
            a0 += bf2f(v.x); a1 += bf2f(v.y); a2 += bf2f(v.z); a3 += bf2f(v.w);
        }
        const float inv = 1.0f / (float)K2;
        const int e0 = lane << 2;
        const int p0 = (e0 >> 3) ^ (r & 7);
        *(ushort4*)&As[r * 512 + (p0 << 3) + (e0 & 7)] = sv;   // self: already bf16
        const int e1 = D + (lane << 2);
        const int p1 = (e1 >> 3) ^ (r & 7);
        *(ushort4*)&As[r * 512 + (p1 << 3) + (e1 & 7)] =
            make_ushort4(f2bf(a0 * inv), f2bf(a1 * inv), f2bf(a2 * inv), f2bf(a3 * inv));
    }

    __syncthreads();

    const unsigned short* bBase = W + (size_t)(wn + l16) * K_DIM + (quad << 3);
    f32x4 acc[4];
    #pragma unroll
    for (int j = 0; j < 4; ++j) acc[j] = (f32x4){0.f, 0.f, 0.f, 0.f};

    #pragma unroll
    for (int t = 0; t < 8; ++t) {
        bf16x8 bp[8];
        #pragma unroll
        for (int ks = 0; ks < 2; ++ks)
            #pragma unroll
            for (int i = 0; i < 4; ++i)
                bp[ks * 4 + i] = *(const bf16x8*)(bBase + (size_t)(i * 16) * K_DIM + t * 64 + ks * 32);
        #pragma unroll
        for (int ks = 0; ks < 2; ++ks) {
            const int ch = (t << 3) + (ks << 2) + quad;
            const bf16x8 af = *(const bf16x8*)&As[l16 * 512 + ((ch ^ (l16 & 7)) << 3)];
            #pragma unroll
            for (int ni = 0; ni < 4; ++ni)
                acc[ni] = __builtin_amdgcn_mfma_f32_16x16x32_bf16(
                    af, bp[ks * 4 + ni], acc[ni], 0, 0, 0);
        }
    }

    #pragma unroll
    for (int ni = 0; ni < 4; ++ni)
        #pragma unroll
        for (int rg = 0; rg < 4; ++rg) {
            const size_t gm = row0 + quad * 4 + rg;
            const size_t gn = (size_t)wn + ni * 16 + l16;
            float v = acc[ni][rg];
            out[gm * D + gn] = v > 0.f ? v : 0.f;
        }
}

extern "C" void kernel_launch(void* const* d_in, const int* in_sizes, int n_in,
                              void* d_out, int out_size, void* d_ws, size_t ws_size,
                              hipStream_t stream) {
    const float* feat        = (const float*)d_in[0];
    const float* W1          = (const float*)d_in[1];
    const float* W2          = (const float*)d_in[2];
    const int*   nodes_batch = (const int*)d_in[3];
    const int*   neigh2      = (const int*)d_in[4];
    const int*   neigh1      = (const int*)d_in[5];
    float* out = (float*)d_out;

    char* ws = (char*)d_ws;
    unsigned*       f8  = (unsigned*)(ws);                    // 51,200,000 B
    unsigned short* h1  = (unsigned short*)(ws + 51200000);   // 23,068,672 B
    unsigned short* W1b = (unsigned short*)(ws + 51200000 + 23068672);           // 262,144 B
    unsigned short* W2b = (unsigned short*)(ws + 51200000 + 23068672 + 262144);  // 262,144 B

    convert_all<<<25000, 256, 0, stream>>>(feat, f8, W1, W2, W1b, W2b);
    fused_l1<<<M_L1 / 32, 512, 0, stream>>>(feat, f8, nodes_batch, neigh2, neigh1, W1b, h1);
    fused_l2<<<B_SZ / 16, 256, 0, stream>>>(h1, W2b, out);
}

// Round 6
// 421.199 us; speedup vs baseline: 1.0481x; 1.0117x over previous
//
#include <hip/hip_runtime.h>
#include <hip/hip_bf16.h>

typedef __attribute__((ext_vector_type(8))) short bf16x8;
typedef __attribute__((ext_vector_type(4))) float f32x4;
typedef __attribute__((ext_vector_type(2))) float f32x2;

#define B_SZ   4096
#define K1     25
#define K2     10
#define M_L1   45056   /* B*(1+K2) */
#define D      256
#define K_DIM  512
#define N_NODES 200000

#define AS1 __attribute__((address_space(1)))
#define AS3 __attribute__((address_space(3)))

static __device__ __forceinline__ unsigned short f2bf(float f) {
    union { float f; unsigned u; } v; v.f = f;
    return (unsigned short)((v.u + 0x7fffu + ((v.u >> 16) & 1u)) >> 16);
}
static __device__ __forceinline__ float bf2f(unsigned short h) {
    union { unsigned u; float f; } v; v.u = ((unsigned)h) << 16;
    return v.f;
}

// ---- convert features fp32 -> fp8 e4m3 (51.2M elems) + W1/W2 -> bf16, one pass ----
__global__ __launch_bounds__(256)
void convert_all(const float* __restrict__ f, unsigned* __restrict__ f8,
                 const float* __restrict__ W1, const float* __restrict__ W2,
                 unsigned short* __restrict__ W1b, unsigned short* __restrict__ W2b) {
    const size_t i = ((size_t)blockIdx.x * 256 + threadIdx.x) * 8;
    const float4 a = *(const float4*)(f + i);
    const float4 b = *(const float4*)(f + i + 4);
    unsigned u0 = 0, u1 = 0;
    u0 = __builtin_amdgcn_cvt_pk_fp8_f32(a.x, a.y, u0, false);
    u0 = __builtin_amdgcn_cvt_pk_fp8_f32(a.z, a.w, u0, true);
    u1 = __builtin_amdgcn_cvt_pk_fp8_f32(b.x, b.y, u1, false);
    u1 = __builtin_amdgcn_cvt_pk_fp8_f32(b.z, b.w, u1, true);
    uint2 r; r.x = u0; r.y = u1;
    *(uint2*)(f8 + (i >> 2)) = r;
    const int j = blockIdx.x * 256 + threadIdx.x;
    if (j < D * K_DIM) {           // 131072 = 256*512 elements each
        W1b[j] = f2bf(W1[j]);
        W2b[j] = f2bf(W2[j]);
    }
}

// ============================================================================
// fused_l1: gather+mean -> LDS A-tile (bf16, XOR-swizzled) + GEMM1 + relu.
//   BM=16, 256 threads (4 waves). LDS = As 16KB + stage 25.6KB = 42KB
//   -> 3 blocks/CU = 12 waves/CU.
//   GATHER (round-6 fix): the 25 f8-row loads per node go through
//   global_load_lds into a per-wave LDS staging buffer — ZERO VGPR
//   destinations, so the register allocator cannot serialize the burst
//   (round 4: VGPR=44 showed it had collapsed the window to ~2 in-flight).
//   25 outstanding loads/wave x 12 waves/CU >> ~45/CU Little's-law need.
//   One vmcnt(0) drains the burst; lgkmcnt(0) guards stage reuse across
//   rows. Readback = 25 conflict-free ds_read_b32 (2 lanes/bank, free).
//   This is the round-1/2-proven staging mechanism, no fragile asm loads.
//   GEMM: B (W1b, L2-resident) via single register buffer bp[8] per K-step.
//   As swizzle: 16B chunk c of row r stored at c^(r&7).
// ============================================================================
__global__ __launch_bounds__(256, 4)
void fused_l1(const float* __restrict__ feat,
              const unsigned* __restrict__ f8,
              const int* __restrict__ nodes_batch,
              const int* __restrict__ neigh2,
              const int* __restrict__ neigh1,
              const unsigned short* __restrict__ W,
              unsigned short* __restrict__ h1) {
    __shared__ unsigned short As[16 * 512];      // 16 KB
    __shared__ unsigned stage[4][K1 * 64];       // 4 waves x 6400 B = 25.6 KB
    const int tid  = threadIdx.x;
    const int w    = tid >> 6, lane = tid & 63;
    const int quad = lane >> 4, l16 = lane & 15;
    const int wn   = w << 6;
    const size_t row0 = (size_t)blockIdx.x * 16;

    // ---- gather + mean -> As: 4 rows per wave, 25-load DMA burst per row ----
    for (int rr = 0; rr < 4; ++rr) {
        const int r = (w << 2) + rr;
        const int m = (int)row0 + r;
        int self_node = (m < B_SZ) ? nodes_batch[m] : neigh2[m - B_SZ];
        self_node = __builtin_amdgcn_readfirstlane(self_node);
        const float4 s = *(const float4*)(feat + (size_t)self_node * D + (lane << 2));
        const int iv = (lane < K1) ? neigh1[(size_t)m * K1 + lane] : 0;

        // guard: previous row's ds_reads of stage[w] must be done before the
        // DMA writes land (cheap; 4x per kernel)
        asm volatile("s_waitcnt lgkmcnt(0)" ::: "memory");
        #pragma unroll
        for (int j = 0; j < K1; ++j) {
            const int n = __builtin_amdgcn_readlane(iv, j);   // SGPR index
            __builtin_amdgcn_global_load_lds(
                (const AS1 void*)(f8 + (size_t)n * (D / 4) + lane),
                (AS3 void*)(&stage[w][j * 64]), 4, 0, 0);
        }
        asm volatile("s_waitcnt vmcnt(0)" ::: "memory");
        __builtin_amdgcn_sched_barrier(0);

        float a0 = 0.f, a1 = 0.f, a2 = 0.f, a3 = 0.f;
        #pragma unroll
        for (int j = 0; j < K1; ++j) {
            const unsigned qj = stage[w][j * 64 + lane];
            const f32x2 lo = __builtin_amdgcn_cvt_pk_f32_fp8(qj, false);
            const f32x2 hi = __builtin_amdgcn_cvt_pk_f32_fp8(qj, true);
            a0 += lo.x; a1 += lo.y; a2 += hi.x; a3 += hi.y;
        }
        const float inv = 1.0f / (float)K1;
        const int e0 = lane << 2;                  // self elems [0,256)
        const int p0 = (e0 >> 3) ^ (r & 7);
        *(ushort4*)&As[r * 512 + (p0 << 3) + (e0 & 7)] =
            make_ushort4(f2bf(s.x), f2bf(s.y), f2bf(s.z), f2bf(s.w));
        const int e1 = D + (lane << 2);            // agg elems [256,512)
        const int p1 = (e1 >> 3) ^ (r & 7);
        *(ushort4*)&As[r * 512 + (p1 << 3) + (e1 & 7)] =
            make_ushort4(f2bf(a0 * inv), f2bf(a1 * inv), f2bf(a2 * inv), f2bf(a3 * inv));
    }

    __syncthreads();

    // ---- GEMM: single-buffered register B, one barrier total ----
    const unsigned short* bBase = W + (size_t)(wn + l16) * K_DIM + (quad << 3);
    f32x4 acc[4];
    #pragma unroll
    for (int j = 0; j < 4; ++j) acc[j] = (f32x4){0.f, 0.f, 0.f, 0.f};

    #pragma unroll
    for (int t = 0; t < 8; ++t) {
        bf16x8 bp[8];
        #pragma unroll
        for (int ks = 0; ks < 2; ++ks)
            #pragma unroll
            for (int i = 0; i < 4; ++i)
                bp[ks * 4 + i] = *(const bf16x8*)(bBase + (size_t)(i * 16) * K_DIM + t * 64 + ks * 32);
        #pragma unroll
        for (int ks = 0; ks < 2; ++ks) {
            const int ch = (t << 3) + (ks << 2) + quad;    // 16B chunk in [0,64)
            const bf16x8 af = *(const bf16x8*)&As[l16 * 512 + ((ch ^ (l16 & 7)) << 3)];
            #pragma unroll
            for (int ni = 0; ni < 4; ++ni)
                acc[ni] = __builtin_amdgcn_mfma_f32_16x16x32_bf16(
                    af, bp[ks * 4 + ni], acc[ni], 0, 0, 0);
        }
    }

    #pragma unroll
    for (int ni = 0; ni < 4; ++ni)
        #pragma unroll
        for (int rg = 0; rg < 4; ++rg) {
            const size_t gm = row0 + quad * 4 + rg;
            const size_t gn = (size_t)wn + ni * 16 + l16;
            float v = acc[ni][rg];
            v = v > 0.f ? v : 0.f;
            h1[gm * D + gn] = f2bf(v);
        }
}

// ============================================================================
// fused_l2: agg2 -> LDS A-tile + GEMM2 + relu -> out (fp32).
//   BM=16, 256 threads (4 waves, each all 16 rows x its 64-col slice).
//   Single-buffered register B, LDS = 16 KB, one barrier.
// ============================================================================
__global__ __launch_bounds__(256, 4)
void fused_l2(const unsigned short* __restrict__ h1,
              const unsigned short* __restrict__ W,
              float* __restrict__ out) {
    __shared__ unsigned short As[16 * 512];      // 16 KB
    const int tid  = threadIdx.x;
    const int w    = tid >> 6, lane = tid & 63;
    const int quad = lane >> 4, l16 = lane & 15;
    const int wn   = w << 6;
    const size_t row0 = (size_t)blockIdx.x * 16;

    // ---- build A-tile: [h1[b] | mean_k h1[B + b*K2 + k]] (4 rows per wave) ----
    #pragma unroll 2
    for (int rr = 0; rr < 4; ++rr) {
        const int r = (w << 2) + rr;
        const size_t b = row0 + r;
        const ushort4 sv = *(const ushort4*)&h1[b * D + (lane << 2)];
        float a0 = 0.f, a1 = 0.f, a2 = 0.f, a3 = 0.f;
        #pragma unroll
        for (int k = 0; k < K2; ++k) {
            const ushort4 v = *(const ushort4*)&h1[(size_t)(B_SZ + b * K2 + k) * D + (lane << 2)];
            a0 += bf2f(v.x); a1 += bf2f(v.y); a2 += bf2f(v.z); a3 += bf2f(v.w);
        }
        const float inv = 1.0f / (float)K2;
        const int e0 = lane << 2;
        const int p0 = (e0 >> 3) ^ (r & 7);
        *(ushort4*)&As[r * 512 + (p0 << 3) + (e0 & 7)] = sv;   // self: already bf16
        const int e1 = D + (lane << 2);
        const int p1 = (e1 >> 3) ^ (r & 7);
        *(ushort4*)&As[r * 512 + (p1 << 3) + (e1 & 7)] =
            make_ushort4(f2bf(a0 * inv), f2bf(a1 * inv), f2bf(a2 * inv), f2bf(a3 * inv));
    }

    __syncthreads();

    const unsigned short* bBase = W + (size_t)(wn + l16) * K_DIM + (quad << 3);
    f32x4 acc[4];
    #pragma unroll
    for (int j = 0; j < 4; ++j) acc[j] = (f32x4){0.f, 0.f, 0.f, 0.f};

    #pragma unroll
    for (int t = 0; t < 8; ++t) {
        bf16x8 bp[8];
        #pragma unroll
        for (int ks = 0; ks < 2; ++ks)
            #pragma unroll
            for (int i = 0; i < 4; ++i)
                bp[ks * 4 + i] = *(const bf16x8*)(bBase + (size_t)(i * 16) * K_DIM + t * 64 + ks * 32);
        #pragma unroll
        for (int ks = 0; ks < 2; ++ks) {
            const int ch = (t << 3) + (ks << 2) + quad;
            const bf16x8 af = *(const bf16x8*)&As[l16 * 512 + ((ch ^ (l16 & 7)) << 3)];
            #pragma unroll
            for (int ni = 0; ni < 4; ++ni)
                acc[ni] = __builtin_amdgcn_mfma_f32_16x16x32_bf16(
                    af, bp[ks * 4 + ni], acc[ni], 0, 0, 0);
        }
    }

    #pragma unroll
    for (int ni = 0; ni < 4; ++ni)
        #pragma unroll
        for (int rg = 0; rg < 4; ++rg) {
            const size_t gm = row0 + quad * 4 + rg;
            const size_t gn = (size_t)wn + ni * 16 + l16;
            float v = acc[ni][rg];
            out[gm * D + gn] = v > 0.f ? v : 0.f;
        }
}

extern "C" void kernel_launch(void* const* d_in, const int* in_sizes, int n_in,
                              void* d_out, int out_size, void* d_ws, size_t ws_size,
                              hipStream_t stream) {
    const float* feat        = (const float*)d_in[0];
    const float* W1          = (const float*)d_in[1];
    const float* W2          = (const float*)d_in[2];
    const int*   nodes_batch = (const int*)d_in[3];
    const int*   neigh2      = (const int*)d_in[4];
    const int*   neigh1      = (const int*)d_in[5];
    float* out = (float*)d_out;

    char* ws = (char*)d_ws;
    unsigned*       f8  = (unsigned*)(ws);                    // 51,200,000 B
    unsigned short* h1  = (unsigned short*)(ws + 51200000);   // 23,068,672 B
    unsigned short* W1b = (unsigned short*)(ws + 51200000 + 23068672);           // 262,144 B
    unsigned short* W2b = (unsigned short*)(ws + 51200000 + 23068672 + 262144);  // 262,144 B

    convert_all<<<25000, 256, 0, stream>>>(feat, f8, W1, W2, W1b, W2b);
    fused_l1<<<M_L1 / 16, 256, 0, stream>>>(feat, f8, nodes_batch, neigh2, neigh1, W1b, h1);
    fused_l2<<<B_SZ / 16, 256, 0, stream>>>(h1, W2b, out);
}

// Round 7
// 383.994 us; speedup vs baseline: 1.1496x; 1.0969x over previous
//
#include <hip/hip_runtime.h>
#include <hip/hip_bf16.h>

typedef __attribute__((ext_vector_type(8))) short bf16x8;
typedef __attribute__((ext_vector_type(4))) float f32x4;
typedef __attribute__((ext_vector_type(2))) float f32x2;

#define B_SZ   4096
#define K1     25
#define K2     10
#define M_L1   45056   /* B*(1+K2) */
#define D      256
#define K_DIM  512
#define N_NODES 200000

#define AS1 __attribute__((address_space(1)))
#define AS3 __attribute__((address_space(3)))

static __device__ __forceinline__ unsigned short f2bf(float f) {
    union { float f; unsigned u; } v; v.f = f;
    return (unsigned short)((v.u + 0x7fffu + ((v.u >> 16) & 1u)) >> 16);
}
static __device__ __forceinline__ float bf2f(unsigned short h) {
    union { unsigned u; float f; } v; v.u = ((unsigned)h) << 16;
    return v.f;
}

// ---- convert features fp32 -> fp8 e4m3 (51.2M elems) + W1/W2 -> bf16, one pass ----
__global__ __launch_bounds__(256)
void convert_all(const float* __restrict__ f, unsigned* __restrict__ f8,
                 const float* __restrict__ W1, const float* __restrict__ W2,
                 unsigned short* __restrict__ W1b, unsigned short* __restrict__ W2b) {
    const size_t i = ((size_t)blockIdx.x * 256 + threadIdx.x) * 8;
    const float4 a = *(const float4*)(f + i);
    const float4 b = *(const float4*)(f + i + 4);
    unsigned u0 = 0, u1 = 0;
    u0 = __builtin_amdgcn_cvt_pk_fp8_f32(a.x, a.y, u0, false);
    u0 = __builtin_amdgcn_cvt_pk_fp8_f32(a.z, a.w, u0, true);
    u1 = __builtin_amdgcn_cvt_pk_fp8_f32(b.x, b.y, u1, false);
    u1 = __builtin_amdgcn_cvt_pk_fp8_f32(b.z, b.w, u1, true);
    uint2 r; r.x = u0; r.y = u1;
    *(uint2*)(f8 + (i >> 2)) = r;
    const int j = blockIdx.x * 256 + threadIdx.x;
    if (j < D * K_DIM) {           // 131072 = 256*512 elements each
        W1b[j] = f2bf(W1[j]);
        W2b[j] = f2bf(W2[j]);
    }
}

// ============================================================================
// fused_l1 — ROUND-2 STRUCTURE (best measured: 365 us total), one delta.
//   grid 704 x 512 threads. LDS: As 64KB (full K=512) + Bs 2x32KB = 128KB.
//   B-tile t=0 issued BEFORE the gather; K-loop = 2-phase pipeline
//   (stage t+1 via global_load_lds, compute t, vmcnt(0)+barrier).
//   DELTA vs round 2 (the only change): gather-phase index loads iv[8] and
//   self-feature loads sf[8] are hoisted ahead of the 25-load bursts
//   (statically indexed, fully unrolled), and index extraction uses
//   v_readlane (SALU) instead of __shfl (ds_bpermute). Removes 8 serial
//   index-load + 8 serial self-load latencies per wave from the gather
//   critical path; burst scheduling freedom otherwise unchanged.
//   As swizzle: 16B chunk c of row r stored at c^(r&7).
// ============================================================================
__global__ __launch_bounds__(512)
void fused_l1(const float* __restrict__ feat,
              const unsigned* __restrict__ f8,
              const int* __restrict__ nodes_batch,
              const int* __restrict__ neigh2,
              const int* __restrict__ neigh1,
              const unsigned short* __restrict__ W,
              unsigned short* __restrict__ h1) {
    __shared__ unsigned short As[64 * 512];      // 64 KB
    __shared__ unsigned short Bs[2][256 * 64];   // 64 KB
    const int tid  = threadIdx.x;
    const int w    = tid >> 6, lane = tid & 63;
    const int quad = lane >> 4, l16 = lane & 15;
    const size_t row0 = (size_t)blockIdx.x * 64;

    // B staging: one call = 8 rows x 64 elems (1KB); swizzle on global source
    const int srow   = lane >> 3;
    const int schunk = ((lane & 7) ^ srow) << 3;
    const unsigned short* bG = W + (size_t)srow * K_DIM + schunk;

    // issue B-tile for k0=0 now; it completes under the gather phase
    #pragma unroll
    for (int c = w; c < 32; c += 8)
        __builtin_amdgcn_global_load_lds(
            (const AS1 void*)(bG + (size_t)(c * 8) * K_DIM),
            (AS3 void*)(&Bs[0][c * 512]), 16, 0, 0);

    // ---- gather + mean -> As (8 rows per wave) ----
    // hoisted: all 8 index vectors + all 8 self-feature rows issued up-front
    int    iv[8];
    float4 sf[8];
    #pragma unroll
    for (int rr = 0; rr < 8; ++rr) {
        const int m = (int)row0 + (w << 3) + rr;
        iv[rr] = (lane < K1) ? neigh1[(size_t)m * K1 + lane] : 0;
    }
    #pragma unroll
    for (int rr = 0; rr < 8; ++rr) {
        const int m = (int)row0 + (w << 3) + rr;
        const int self_node = (m < B_SZ) ? nodes_batch[m] : neigh2[m - B_SZ];
        sf[rr] = *(const float4*)(feat + (size_t)self_node * D + (lane << 2));
    }
    #pragma unroll 2
    for (int rr = 0; rr < 8; ++rr) {
        const int r = (w << 3) + rr;
        unsigned q[K1];
        #pragma unroll
        for (int j = 0; j < K1; ++j) {
            const int node = __builtin_amdgcn_readlane(iv[rr], j);   // SALU
            q[j] = f8[(size_t)node * (D / 4) + lane];
        }
        float a0 = 0.f, a1 = 0.f, a2 = 0.f, a3 = 0.f;
        #pragma unroll
        for (int j = 0; j < K1; ++j) {
            const f32x2 lo = __builtin_amdgcn_cvt_pk_f32_fp8(q[j], false);
            const f32x2 hi = __builtin_amdgcn_cvt_pk_f32_fp8(q[j], true);
            a0 += lo.x; a1 += lo.y; a2 += hi.x; a3 += hi.y;
        }
        const float inv = 1.0f / (float)K1;
        const int e0 = lane << 2;                  // self elems [0,256)
        const int p0 = (e0 >> 3) ^ (r & 7);
        *(ushort4*)&As[r * 512 + (p0 << 3) + (e0 & 7)] =
            make_ushort4(f2bf(sf[rr].x), f2bf(sf[rr].y), f2bf(sf[rr].z), f2bf(sf[rr].w));
        const int e1 = D + (lane << 2);            // agg elems [256,512)
        const int p1 = (e1 >> 3) ^ (r & 7);
        *(ushort4*)&As[r * 512 + (p1 << 3) + (e1 & 7)] =
            make_ushort4(f2bf(a0 * inv), f2bf(a1 * inv), f2bf(a2 * inv), f2bf(a3 * inv));
    }

    asm volatile("s_waitcnt vmcnt(0)" ::: "memory");
    __syncthreads();

    // ---- GEMM: 8 waves = 2M x 4N; each wave 32 rows x 64 cols ----
    const int wm = (w >> 2) << 5;   // 0 / 32
    const int wn = (w & 3) << 6;    // 0,64,128,192
    f32x4 acc[2][4];
    #pragma unroll
    for (int i = 0; i < 2; ++i)
        #pragma unroll
        for (int j = 0; j < 4; ++j)
            acc[i][j] = (f32x4){0.f, 0.f, 0.f, 0.f};

    for (int t = 0; t < 8; ++t) {
        if (t < 7) {
            #pragma unroll
            for (int c = w; c < 32; c += 8)
                __builtin_amdgcn_global_load_lds(
                    (const AS1 void*)(bG + (size_t)(c * 8) * K_DIM + ((t + 1) << 6)),
                    (AS3 void*)(&Bs[(t + 1) & 1][c * 512]), 16, 0, 0);
        }
        #pragma unroll
        for (int ks = 0; ks < 2; ++ks) {
            bf16x8 af[2], bfr[4];
            #pragma unroll
            for (int i = 0; i < 2; ++i) {
                const int row = wm + i * 16 + l16;
                const int ch  = (t << 3) + (ks << 2) + quad;   // 16B chunk in [0,64)
                af[i] = *(const bf16x8*)&As[row * 512 + ((ch ^ (row & 7)) << 3)];
            }
            #pragma unroll
            for (int i = 0; i < 4; ++i) {
                const int row = wn + i * 16 + l16;
                bfr[i] = *(const bf16x8*)&Bs[t & 1][row * 64 + ((((ks << 2) + quad) ^ (l16 & 7)) << 3)];
            }
            #pragma unroll
            for (int mi = 0; mi < 2; ++mi)
                #pragma unroll
                for (int ni = 0; ni < 4; ++ni)
                    acc[mi][ni] = __builtin_amdgcn_mfma_f32_16x16x32_bf16(
                        af[mi], bfr[ni], acc[mi][ni], 0, 0, 0);
        }
        asm volatile("s_waitcnt vmcnt(0)" ::: "memory");
        __syncthreads();
    }

    #pragma unroll
    for (int mi = 0; mi < 2; ++mi)
        #pragma unroll
        for (int ni = 0; ni < 4; ++ni)
            #pragma unroll
            for (int rg = 0; rg < 4; ++rg) {
                const size_t gm = row0 + wm + mi * 16 + quad * 4 + rg;
                const size_t gn = (size_t)wn + ni * 16 + l16;
                float v = acc[mi][ni][rg];
                v = v > 0.f ? v : 0.f;
                h1[gm * D + gn] = f2bf(v);
            }
}

// ============================================================================
// fused_l2 — ROUND-2 VERSION (byte-identical): agg2 -> LDS A-tile + GEMM2.
//   grid 256 x 256 threads, BM=16. LDS: As 16KB + Bs 2x32KB = 80KB
//   (2 blocks/CU).
// ============================================================================
__global__ __launch_bounds__(256)
void fused_l2(const unsigned short* __restrict__ h1,
              const unsigned short* __restrict__ W,
              float* __restrict__ out) {
    __shared__ unsigned short As[16 * 512];      // 16 KB
    __shared__ unsigned short Bs[2][256 * 64];   // 64 KB
    const int tid  = threadIdx.x;
    const int w    = tid >> 6, lane = tid & 63;
    const int quad = lane >> 4, l16 = lane & 15;
    const size_t row0 = (size_t)blockIdx.x * 16;

    const int srow   = lane >> 3;
    const int schunk = ((lane & 7) ^ srow) << 3;
    const unsigned short* bG = W + (size_t)srow * K_DIM + schunk;

    #pragma unroll
    for (int c = w; c < 32; c += 4)
        __builtin_amdgcn_global_load_lds(
            (const AS1 void*)(bG + (size_t)(c * 8) * K_DIM),
            (AS3 void*)(&Bs[0][c * 512]), 16, 0, 0);

    // ---- build A-tile: [h1[b] | mean_k h1[B + b*K2 + k]] ----
    #pragma unroll
    for (int rr = 0; rr < 4; ++rr) {
        const int r = (w << 2) + rr;
        const size_t b = row0 + r;
        const ushort4 sv = *(const ushort4*)&h1[b * D + (lane << 2)];
        float a0 = 0.f, a1 = 0.f, a2 = 0.f, a3 = 0.f;
        #pragma unroll
        for (int k = 0; k < K2; ++k) {
            const ushort4 v = *(const ushort4*)&h1[(size_t)(B_SZ + b * K2 + k) * D + (lane << 2)];
            a0 += bf2f(v.x); a1 += bf2f(v.y); a2 += bf2f(v.z); a3 += bf2f(v.w);
        }
        const float inv = 1.0f / (float)K2;
        const int e0 = lane << 2;
        const int p0 = (e0 >> 3) ^ (r & 7);
        *(ushort4*)&As[r * 512 + (p0 << 3) + (e0 & 7)] = sv;   // self: already bf16
        const int e1 = D + (lane << 2);
        const int p1 = (e1 >> 3) ^ (r & 7);
        *(ushort4*)&As[r * 512 + (p1 << 3) + (e1 & 7)] =
            make_ushort4(f2bf(a0 * inv), f2bf(a1 * inv), f2bf(a2 * inv), f2bf(a3 * inv));
    }

    asm volatile("s_waitcnt vmcnt(0)" ::: "memory");
    __syncthreads();

    const int wn = w << 6;          // each wave: all 16 rows x its 64-col slice
    f32x4 acc[4];
    #pragma unroll
    for (int j = 0; j < 4; ++j) acc[j] = (f32x4){0.f, 0.f, 0.f, 0.f};

    for (int t = 0; t < 8; ++t) {
        if (t < 7) {
            #pragma unroll
            for (int c = w; c < 32; c += 4)
                __builtin_amdgcn_global_load_lds(
                    (const AS1 void*)(bG + (size_t)(c * 8) * K_DIM + ((t + 1) << 6)),
                    (AS3 void*)(&Bs[(t + 1) & 1][c * 512]), 16, 0, 0);
        }
        #pragma unroll
        for (int ks = 0; ks < 2; ++ks) {
            const int ch = (t << 3) + (ks << 2) + quad;
            const bf16x8 af = *(const bf16x8*)&As[l16 * 512 + ((ch ^ (l16 & 7)) << 3)];
            bf16x8 bfr[4];
            #pragma unroll
            for (int i = 0; i < 4; ++i) {
                const int row = wn + i * 16 + l16;
                bfr[i] = *(const bf16x8*)&Bs[t & 1][row * 64 + ((((ks << 2) + quad) ^ (l16 & 7)) << 3)];
            }
            #pragma unroll
            for (int ni = 0; ni < 4; ++ni)
                acc[ni] = __builtin_amdgcn_mfma_f32_16x16x32_bf16(af, bfr[ni], acc[ni], 0, 0, 0);
        }
        asm volatile("s_waitcnt vmcnt(0)" ::: "memory");
        __syncthreads();
    }

    #pragma unroll
    for (int ni = 0; ni < 4; ++ni)
        #pragma unroll
        for (int rg = 0; rg < 4; ++rg) {
            const size_t gm = row0 + quad * 4 + rg;
            const size_t gn = (size_t)wn + ni * 16 + l16;
            float v = acc[ni][rg];
            out[gm * D + gn] = v > 0.f ? v : 0.f;
        }
}

extern "C" void kernel_launch(void* const* d_in, const int* in_sizes, int n_in,
                              void* d_out, int out_size, void* d_ws, size_t ws_size,
                              hipStream_t stream) {
    const float* feat        = (const float*)d_in[0];
    const float* W1          = (const float*)d_in[1];
    const float* W2          = (const float*)d_in[2];
    const int*   nodes_batch = (const int*)d_in[3];
    const int*   neigh2      = (const int*)d_in[4];
    const int*   neigh1      = (const int*)d_in[5];
    float* out = (float*)d_out;

    char* ws = (char*)d_ws;
    unsigned*       f8  = (unsigned*)(ws);                    // 51,200,000 B
    unsigned short* h1  = (unsigned short*)(ws + 51200000);   // 23,068,672 B
    unsigned short* W1b = (unsigned short*)(ws + 51200000 + 23068672);           // 262,144 B
    unsigned short* W2b = (unsigned short*)(ws + 51200000 + 23068672 + 262144);  // 262,144 B

    convert_all<<<25000, 256, 0, stream>>>(feat, f8, W1, W2, W1b, W2b);
    fused_l1<<<M_L1 / 64, 512, 0, stream>>>(feat, f8, nodes_batch, neigh2, neigh1, W1b, h1);
    fused_l2<<<B_SZ / 16, 256, 0, stream>>>(h1, W2b, out);
}

// Round 8
// 381.883 us; speedup vs baseline: 1.1560x; 1.0055x over previous
//
#include <hip/hip_runtime.h>
#include <hip/hip_bf16.h>

typedef __attribute__((ext_vector_type(8))) short bf16x8;
typedef __attribute__((ext_vector_type(4))) float f32x4;
typedef __attribute__((ext_vector_type(2))) float f32x2;

#define B_SZ   4096
#define K1     25
#define K2     10
#define M_L1   45056   /* B*(1+K2) */
#define D      256
#define K_DIM  512
#define N_NODES 200000

#define AS1 __attribute__((address_space(1)))
#define AS3 __attribute__((address_space(3)))

static __device__ __forceinline__ unsigned short f2bf(float f) {
    union { float f; unsigned u; } v; v.f = f;
    return (unsigned short)((v.u + 0x7fffu + ((v.u >> 16) & 1u)) >> 16);
}
static __device__ __forceinline__ float bf2f(unsigned short h) {
    union { unsigned u; float f; } v; v.u = ((unsigned)h) << 16;
    return v.f;
}

// ---- convert features fp32 -> fp8 e4m3 (51.2M elems) + W1/W2 -> bf16, one pass ----
__global__ __launch_bounds__(256)
void convert_all(const float* __restrict__ f, unsigned* __restrict__ f8,
                 const float* __restrict__ W1, const float* __restrict__ W2,
                 unsigned short* __restrict__ W1b, unsigned short* __restrict__ W2b) {
    const size_t i = ((size_t)blockIdx.x * 256 + threadIdx.x) * 8;
    const float4 a = *(const float4*)(f + i);
    const float4 b = *(const float4*)(f + i + 4);
    unsigned u0 = 0, u1 = 0;
    u0 = __builtin_amdgcn_cvt_pk_fp8_f32(a.x, a.y, u0, false);
    u0 = __builtin_amdgcn_cvt_pk_fp8_f32(a.z, a.w, u0, true);
    u1 = __builtin_amdgcn_cvt_pk_fp8_f32(b.x, b.y, u1, false);
    u1 = __builtin_amdgcn_cvt_pk_fp8_f32(b.z, b.w, u1, true);
    uint2 r; r.x = u0; r.y = u1;
    *(uint2*)(f8 + (i >> 2)) = r;
    const int j = blockIdx.x * 256 + threadIdx.x;
    if (j < D * K_DIM) {           // 131072 = 256*512 elements each
        W1b[j] = f2bf(W1[j]);
        W2b[j] = f2bf(W2[j]);
    }
}

// ============================================================================
// fused_l1 — ROUND-2 STRUCTURE byte-exact (best measured: 365 us total),
//   with ONE delta: the 25 f8 gather loads are NON-TEMPORAL
//   (__builtin_nontemporal_load -> 'nt' modifier, no L1 line allocation).
//   Theory: 288 MB of random 256B-granule reads thrash the 32KB TCP with
//   ~0% reuse; line allocation/fill competes with B-staging and self-feat
//   lines and throttles the gather at ~70 cy/row/CU (invariant across 3
//   issue mechanisms in rounds 2/4/6 -> not issue- or occupancy-bound).
//   grid 704 x 512 threads. LDS: As 64KB (full K=512) + Bs 2x32KB = 128KB.
//   B-tile t=0 issued BEFORE the gather; K-loop = 2-phase pipeline
//   (stage t+1 via global_load_lds, compute t, vmcnt(0)+barrier).
//   As swizzle: 16B chunk c of row r stored at c^(r&7).
// ============================================================================
__global__ __launch_bounds__(512)
void fused_l1(const float* __restrict__ feat,
              const unsigned* __restrict__ f8,
              const int* __restrict__ nodes_batch,
              const int* __restrict__ neigh2,
              const int* __restrict__ neigh1,
              const unsigned short* __restrict__ W,
              unsigned short* __restrict__ h1) {
    __shared__ unsigned short As[64 * 512];      // 64 KB
    __shared__ unsigned short Bs[2][256 * 64];   // 64 KB
    const int tid  = threadIdx.x;
    const int w    = tid >> 6, lane = tid & 63;
    const int quad = lane >> 4, l16 = lane & 15;
    const size_t row0 = (size_t)blockIdx.x * 64;

    // B staging: one call = 8 rows x 64 elems (1KB); swizzle on global source
    const int srow   = lane >> 3;
    const int schunk = ((lane & 7) ^ srow) << 3;
    const unsigned short* bG = W + (size_t)srow * K_DIM + schunk;

    // issue B-tile for k0=0 now; it completes under the gather phase
    #pragma unroll
    for (int c = w; c < 32; c += 8)
        __builtin_amdgcn_global_load_lds(
            (const AS1 void*)(bG + (size_t)(c * 8) * K_DIM),
            (AS3 void*)(&Bs[0][c * 512]), 16, 0, 0);

    // ---- gather + mean -> As ----
    #pragma unroll 2
    for (int rr = 0; rr < 8; ++rr) {
        const int r = (w << 3) + rr;
        const int m = (int)row0 + r;
        const int self_node = (m < B_SZ) ? nodes_batch[m] : neigh2[m - B_SZ];
        const int* nb = neigh1 + (size_t)m * K1;
        int idxv = (lane < K1) ? nb[lane] : 0;
        const float4 s = *(const float4*)(feat + (size_t)self_node * D + (lane << 2));
        unsigned q[K1];
        #pragma unroll
        for (int j = 0; j < K1; ++j) {
            const int node = __shfl(idxv, j);
            q[j] = __builtin_nontemporal_load(f8 + (size_t)node * (D / 4) + lane);
        }
        float a0 = 0.f, a1 = 0.f, a2 = 0.f, a3 = 0.f;
        #pragma unroll
        for (int j = 0; j < K1; ++j) {
            const f32x2 lo = __builtin_amdgcn_cvt_pk_f32_fp8(q[j], false);
            const f32x2 hi = __builtin_amdgcn_cvt_pk_f32_fp8(q[j], true);
            a0 += lo.x; a1 += lo.y; a2 += hi.x; a3 += hi.y;
        }
        const float inv = 1.0f / (float)K1;
        const int e0 = lane << 2;                  // self elems [0,256)
        const int p0 = (e0 >> 3) ^ (r & 7);
        *(ushort4*)&As[r * 512 + (p0 << 3) + (e0 & 7)] =
            make_ushort4(f2bf(s.x), f2bf(s.y), f2bf(s.z), f2bf(s.w));
        const int e1 = D + (lane << 2);            // agg elems [256,512)
        const int p1 = (e1 >> 3) ^ (r & 7);
        *(ushort4*)&As[r * 512 + (p1 << 3) + (e1 & 7)] =
            make_ushort4(f2bf(a0 * inv), f2bf(a1 * inv), f2bf(a2 * inv), f2bf(a3 * inv));
    }

    asm volatile("s_waitcnt vmcnt(0)" ::: "memory");
    __syncthreads();

    // ---- GEMM: 8 waves = 2M x 4N; each wave 32 rows x 64 cols ----
    const int wm = (w >> 2) << 5;   // 0 / 32
    const int wn = (w & 3) << 6;    // 0,64,128,192
    f32x4 acc[2][4];
    #pragma unroll
    for (int i = 0; i < 2; ++i)
        #pragma unroll
        for (int j = 0; j < 4; ++j)
            acc[i][j] = (f32x4){0.f, 0.f, 0.f, 0.f};

    for (int t = 0; t < 8; ++t) {
        if (t < 7) {
            #pragma unroll
            for (int c = w; c < 32; c += 8)
                __builtin_amdgcn_global_load_lds(
                    (const AS1 void*)(bG + (size_t)(c * 8) * K_DIM + ((t + 1) << 6)),
                    (AS3 void*)(&Bs[(t + 1) & 1][c * 512]), 16, 0, 0);
        }
        #pragma unroll
        for (int ks = 0; ks < 2; ++ks) {
            bf16x8 af[2], bfr[4];
            #pragma unroll
            for (int i = 0; i < 2; ++i) {
                const int row = wm + i * 16 + l16;
                const int ch  = (t << 3) + (ks << 2) + quad;   // 16B chunk in [0,64)
                af[i] = *(const bf16x8*)&As[row * 512 + ((ch ^ (row & 7)) << 3)];
            }
            #pragma unroll
            for (int i = 0; i < 4; ++i) {
                const int row = wn + i * 16 + l16;
                bfr[i] = *(const bf16x8*)&Bs[t & 1][row * 64 + ((((ks << 2) + quad) ^ (l16 & 7)) << 3)];
            }
            #pragma unroll
            for (int mi = 0; mi < 2; ++mi)
                #pragma unroll
                for (int ni = 0; ni < 4; ++ni)
                    acc[mi][ni] = __builtin_amdgcn_mfma_f32_16x16x32_bf16(
                        af[mi], bfr[ni], acc[mi][ni], 0, 0, 0);
        }
        asm volatile("s_waitcnt vmcnt(0)" ::: "memory");
        __syncthreads();
    }

    #pragma unroll
    for (int mi = 0; mi < 2; ++mi)
        #pragma unroll
        for (int ni = 0; ni < 4; ++ni)
            #pragma unroll
            for (int rg = 0; rg < 4; ++rg) {
                const size_t gm = row0 + wm + mi * 16 + quad * 4 + rg;
                const size_t gn = (size_t)wn + ni * 16 + l16;
                float v = acc[mi][ni][rg];
                v = v > 0.f ? v : 0.f;
                h1[gm * D + gn] = f2bf(v);
            }
}

// ============================================================================
// fused_l2 — ROUND-2 VERSION (byte-identical): agg2 -> LDS A-tile + GEMM2.
//   grid 256 x 256 threads, BM=16. LDS: As 16KB + Bs 2x32KB = 80KB
//   (2 blocks/CU).
// ============================================================================
__global__ __launch_bounds__(256)
void fused_l2(const unsigned short* __restrict__ h1,
              const unsigned short* __restrict__ W,
              float* __restrict__ out) {
    __shared__ unsigned short As[16 * 512];      // 16 KB
    __shared__ unsigned short Bs[2][256 * 64];   // 64 KB
    const int tid  = threadIdx.x;
    const int w    = tid >> 6, lane = tid & 63;
    const int quad = lane >> 4, l16 = lane & 15;
    const size_t row0 = (size_t)blockIdx.x * 16;

    const int srow   = lane >> 3;
    const int schunk = ((lane & 7) ^ srow) << 3;
    const unsigned short* bG = W + (size_t)srow * K_DIM + schunk;

    #pragma unroll
    for (int c = w; c < 32; c += 4)
        __builtin_amdgcn_global_load_lds(
            (const AS1 void*)(bG + (size_t)(c * 8) * K_DIM),
            (AS3 void*)(&Bs[0][c * 512]), 16, 0, 0);

    // ---- build A-tile: [h1[b] | mean_k h1[B + b*K2 + k]] ----
    #pragma unroll
    for (int rr = 0; rr < 4; ++rr) {
        const int r = (w << 2) + rr;
        const size_t b = row0 + r;
        const ushort4 sv = *(const ushort4*)&h1[b * D + (lane << 2)];
        float a0 = 0.f, a1 = 0.f, a2 = 0.f, a3 = 0.f;
        #pragma unroll
        for (int k = 0; k < K2; ++k) {
            const ushort4 v = *(const ushort4*)&h1[(size_t)(B_SZ + b * K2 + k) * D + (lane << 2)];
            a0 += bf2f(v.x); a1 += bf2f(v.y); a2 += bf2f(v.z); a3 += bf2f(v.w);
        }
        const float inv = 1.0f / (float)K2;
        const int e0 = lane << 2;
        const int p0 = (e0 >> 3) ^ (r & 7);
        *(ushort4*)&As[r * 512 + (p0 << 3) + (e0 & 7)] = sv;   // self: already bf16
        const int e1 = D + (lane << 2);
        const int p1 = (e1 >> 3) ^ (r & 7);
        *(ushort4*)&As[r * 512 + (p1 << 3) + (e1 & 7)] =
            make_ushort4(f2bf(a0 * inv), f2bf(a1 * inv), f2bf(a2 * inv), f2bf(a3 * inv));
    }

    asm volatile("s_waitcnt vmcnt(0)" ::: "memory");
    __syncthreads();

    const int wn = w << 6;          // each wave: all 16 rows x its 64-col slice
    f32x4 acc[4];
    #pragma unroll
    for (int j = 0; j < 4; ++j) acc[j] = (f32x4){0.f, 0.f, 0.f, 0.f};

    for (int t = 0; t < 8; ++t) {
        if (t < 7) {
            #pragma unroll
            for (int c = w; c < 32; c += 4)
                __builtin_amdgcn_global_load_lds(
                    (const AS1 void*)(bG + (size_t)(c * 8) * K_DIM + ((t + 1) << 6)),
                    (AS3 void*)(&Bs[(t + 1) & 1][c * 512]), 16, 0, 0);
        }
        #pragma unroll
        for (int ks = 0; ks < 2; ++ks) {
            const int ch = (t << 3) + (ks << 2) + quad;
            const bf16x8 af = *(const bf16x8*)&As[l16 * 512 + ((ch ^ (l16 & 7)) << 3)];
            bf16x8 bfr[4];
            #pragma unroll
            for (int i = 0; i < 4; ++i) {
                const int row = wn + i * 16 + l16;
                bfr[i] = *(const bf16x8*)&Bs[t & 1][row * 64 + ((((ks << 2) + quad) ^ (l16 & 7)) << 3)];
            }
            #pragma unroll
            for (int ni = 0; ni < 4; ++ni)
                acc[ni] = __builtin_amdgcn_mfma_f32_16x16x32_bf16(af, bfr[ni], acc[ni], 0, 0, 0);
        }
        asm volatile("s_waitcnt vmcnt(0)" ::: "memory");
        __syncthreads();
    }

    #pragma unroll
    for (int ni = 0; ni < 4; ++ni)
        #pragma unroll
        for (int rg = 0; rg < 4; ++rg) {
            const size_t gm = row0 + quad * 4 + rg;
            const size_t gn = (size_t)wn + ni * 16 + l16;
            float v = acc[ni][rg];
            out[gm * D + gn] = v > 0.f ? v : 0.f;
        }
}

extern "C" void kernel_launch(void* const* d_in, const int* in_sizes, int n_in,
                              void* d_out, int out_size, void* d_ws, size_t ws_size,
                              hipStream_t stream) {
    const float* feat        = (const float*)d_in[0];
    const float* W1          = (const float*)d_in[1];
    const float* W2          = (const float*)d_in[2];
    const int*   nodes_batch = (const int*)d_in[3];
    const int*   neigh2      = (const int*)d_in[4];
    const int*   neigh1      = (const int*)d_in[5];
    float* out = (float*)d_out;

    char* ws = (char*)d_ws;
    unsigned*       f8  = (unsigned*)(ws);                    // 51,200,000 B
    unsigned short* h1  = (unsigned short*)(ws + 51200000);   // 23,068,672 B
    unsigned short* W1b = (unsigned short*)(ws + 51200000 + 23068672);           // 262,144 B
    unsigned short* W2b = (unsigned short*)(ws + 51200000 + 23068672 + 262144);  // 262,144 B

    convert_all<<<25000, 256, 0, stream>>>(feat, f8, W1, W2, W1b, W2b);
    fused_l1<<<M_L1 / 64, 512, 0, stream>>>(feat, f8, nodes_batch, neigh2, neigh1, W1b, h1);
    fused_l2<<<B_SZ / 16, 256, 0, stream>>>(h1, W2b, out);
}